// Round 2
// baseline (243.453 us; speedup 1.0000x reference)
//
#include <hip/hip_runtime.h>

#define NXD 4096
#define NYD 4096

typedef float f32x4 __attribute__((ext_vector_type(4)));

// R2: ROWS=2 all-upfront loads (R1 winner) + XCD-banded block swizzle.
// MI355X dispatches consecutive block ids round-robin across 8 XCDs, so a
// strip and its vertical neighbor land on different XCDs -> every halo row
// read (50% of read traffic at ROWS=2) misses that XCD's private L2.
// Remap so XCD c owns rows [c*512, (c+1)*512): halo reads become same-XCD
// L2 hits, cutting average read latency -> higher queue-limited equilibrium BW.
__global__ __launch_bounds__(256) void DiffReactParamPDE_85478439125433_kernel(
    const float* __restrict__ state,
    const float* __restrict__ bc,
    const float* __restrict__ a_org,
    const float* __restrict__ b_org,
    const float* __restrict__ k_org,
    float* __restrict__ out)
{
    const float inv_dx2 = 100.0f;

    // ---- XCD-aware swizzle (bijective: 8192 blocks % 8 == 0) ----
    // hw: xcd = bid % 8. Give each xcd a contiguous chunk of the row space.
    const int bid   = blockIdx.x;          // 0..8191, 1-D grid
    const int xcd   = bid & 7;
    const int chunk = bid >> 3;            // 0..1023
    const int nl    = xcd * 1024 + chunk;  // new linear id
    const int bx    = nl & 3;              // 0..3   (col tile)
    const int by    = nl >> 2;             // 0..2047 (row strip)

    const int lane = threadIdx.x & 63;
    const int j0 = (bx * 256 + threadIdx.x) * 4;  // 4 cols per thread
    const int i0 = by * 2;                        // 2 output rows per thread

    const float* __restrict__ U = state;
    const float* __restrict__ V = state + (size_t)NXD * NYD;
    float* __restrict__ dU = out;
    float* __restrict__ dV = out + (size_t)NXD * NYD;

    // Clamp halo row indices so loads are unconditional (issue back-to-back);
    // boundary values get patched with bc after the loads are in flight.
    const int rT = (i0 == 0) ? 0 : i0 - 1;
    const int rB = (i0 + 2 >= NXD) ? NXD - 1 : i0 + 2;

#define LD4(P, ROW) (*(const float4*)((P) + (size_t)(ROW) * NYD + j0))
    // ---- issue all 8 row loads up front ----
    float4 um = LD4(U, rT);
    float4 u0 = LD4(U, i0);
    float4 u1 = LD4(U, i0 + 1);
    float4 up = LD4(U, rB);
    float4 vm = LD4(V, rT);
    float4 v0 = LD4(V, i0);
    float4 v1 = LD4(V, i0 + 1);
    float4 vp = LD4(V, rB);
#undef LD4

    // bc (1,2,4): [U: L,R,T,B | V: L,R,T,B] -- uniform address -> s_load
    const float uL = bc[0], uR = bc[1], uT = bc[2], uB = bc[3];
    const float vL = bc[4], vR = bc[5], vT = bc[6], vB = bc[7];

    // ---- edge scalars for both compute rows, issued up front ----
    float eLu0 = uL, eLu1 = uL, eLv0 = vL, eLv1 = vL;
    float eRu0 = uR, eRu1 = uR, eRv0 = vR, eRv1 = vR;
    if (lane == 0 && j0 > 0) {
        eLu0 = U[(size_t)i0 * NYD + j0 - 1];
        eLu1 = U[(size_t)(i0 + 1) * NYD + j0 - 1];
        eLv0 = V[(size_t)i0 * NYD + j0 - 1];
        eLv1 = V[(size_t)(i0 + 1) * NYD + j0 - 1];
    }
    if (lane == 63 && j0 + 4 < NYD) {
        eRu0 = U[(size_t)i0 * NYD + j0 + 4];
        eRu1 = U[(size_t)(i0 + 1) * NYD + j0 + 4];
        eRv0 = V[(size_t)i0 * NYD + j0 + 4];
        eRv1 = V[(size_t)(i0 + 1) * NYD + j0 + 4];
    }

    // scalar params (uniform -> scalar pipe, overlaps with vector loads)
    const float a = 0.01f / (1.0f + expf(-a_org[0]));
    const float b = 0.01f / (1.0f + expf(-b_org[0]));
    const float k = 0.01f / (1.0f + expf(-k_org[0]));

    // ---- patch halo rows with bc (block-uniform branches) ----
    if (i0 == 0) {
        um = make_float4(uT, uT, uT, uT);
        vm = make_float4(vT, vT, vT, vT);
    }
    if (i0 + 2 >= NXD) {
        up = make_float4(uB, uB, uB, uB);
        vp = make_float4(vB, vB, vB, vB);
    }

    // =================== row 0 (i0): neighbors um / u1 ===================
    {
        float ulft = __shfl_up(u0.w, 1);   if (lane == 0)  ulft = eLu0;
        float urgt = __shfl_down(u0.x, 1); if (lane == 63) urgt = eRu0;
        float vlft = __shfl_up(v0.w, 1);   if (lane == 0)  vlft = eLv0;
        float vrgt = __shfl_down(v0.x, 1); if (lane == 63) vrgt = eRv0;

        const float lu0 = (um.x + u1.x + ulft + u0.y - 4.0f * u0.x) * inv_dx2;
        const float lu1 = (um.y + u1.y + u0.x + u0.z - 4.0f * u0.y) * inv_dx2;
        const float lu2 = (um.z + u1.z + u0.y + u0.w - 4.0f * u0.z) * inv_dx2;
        const float lu3 = (um.w + u1.w + u0.z + urgt - 4.0f * u0.w) * inv_dx2;

        const float lv0 = (vm.x + v1.x + vlft + v0.y - 4.0f * v0.x) * inv_dx2;
        const float lv1 = (vm.y + v1.y + v0.x + v0.z - 4.0f * v0.y) * inv_dx2;
        const float lv2 = (vm.z + v1.z + v0.y + v0.w - 4.0f * v0.z) * inv_dx2;
        const float lv3 = (vm.w + v1.w + v0.z + vrgt - 4.0f * v0.w) * inv_dx2;

        f32x4 duo, dvo;
        duo.x = a * lu0 + u0.x - u0.x * u0.x * u0.x - v0.x - k;
        duo.y = a * lu1 + u0.y - u0.y * u0.y * u0.y - v0.y - k;
        duo.z = a * lu2 + u0.z - u0.z * u0.z * u0.z - v0.z - k;
        duo.w = a * lu3 + u0.w - u0.w * u0.w * u0.w - v0.w - k;

        dvo.x = b * lv0 + u0.x - v0.x;
        dvo.y = b * lv1 + u0.y - v0.y;
        dvo.z = b * lv2 + u0.z - v0.z;
        dvo.w = b * lv3 + u0.w - v0.w;

        const size_t bo = (size_t)i0 * NYD + j0;
        __builtin_nontemporal_store(duo, (f32x4*)(dU + bo));
        __builtin_nontemporal_store(dvo, (f32x4*)(dV + bo));
    }

    // =================== row 1 (i0+1): neighbors u0 / up ===================
    {
        float ulft = __shfl_up(u1.w, 1);   if (lane == 0)  ulft = eLu1;
        float urgt = __shfl_down(u1.x, 1); if (lane == 63) urgt = eRu1;
        float vlft = __shfl_up(v1.w, 1);   if (lane == 0)  vlft = eLv1;
        float vrgt = __shfl_down(v1.x, 1); if (lane == 63) vrgt = eRv1;

        const float lu0 = (u0.x + up.x + ulft + u1.y - 4.0f * u1.x) * inv_dx2;
        const float lu1 = (u0.y + up.y + u1.x + u1.z - 4.0f * u1.y) * inv_dx2;
        const float lu2 = (u0.z + up.z + u1.y + u1.w - 4.0f * u1.z) * inv_dx2;
        const float lu3 = (u0.w + up.w + u1.z + urgt - 4.0f * u1.w) * inv_dx2;

        const float lv0 = (v0.x + vp.x + vlft + v1.y - 4.0f * v1.x) * inv_dx2;
        const float lv1 = (v0.y + vp.y + v1.x + v1.z - 4.0f * v1.y) * inv_dx2;
        const float lv2 = (v0.z + vp.z + v1.y + v1.w - 4.0f * v1.z) * inv_dx2;
        const float lv3 = (v0.w + vp.w + v1.z + vrgt - 4.0f * v1.w) * inv_dx2;

        f32x4 duo, dvo;
        duo.x = a * lu0 + u1.x - u1.x * u1.x * u1.x - v1.x - k;
        duo.y = a * lu1 + u1.y - u1.y * u1.y * u1.y - v1.y - k;
        duo.z = a * lu2 + u1.z - u1.z * u1.z * u1.z - v1.z - k;
        duo.w = a * lu3 + u1.w - u1.w * u1.w * u1.w - v1.w - k;

        dvo.x = b * lv0 + u1.x - v1.x;
        dvo.y = b * lv1 + u1.y - v1.y;
        dvo.z = b * lv2 + u1.z - v1.z;
        dvo.w = b * lv3 + u1.w - v1.w;

        const size_t bo = (size_t)(i0 + 1) * NYD + j0;
        __builtin_nontemporal_store(duo, (f32x4*)(dU + bo));
        __builtin_nontemporal_store(dvo, (f32x4*)(dV + bo));
    }
}

extern "C" void kernel_launch(void* const* d_in, const int* in_sizes, int n_in,
                              void* d_out, int out_size, void* d_ws, size_t ws_size,
                              hipStream_t stream) {
    const float* state = (const float*)d_in[0];
    const float* bc    = (const float*)d_in[1];
    const float* a_org = (const float*)d_in[2];
    const float* b_org = (const float*)d_in[3];
    const float* k_org = (const float*)d_in[4];
    float* out = (float*)d_out;

    // 1-D grid of 8192 blocks: 4 col-tiles x 2048 row-strips, swizzled in-kernel.
    dim3 block(256, 1, 1);
    dim3 grid((NYD / (4 * 256)) * (NXD / 2), 1, 1);
    DiffReactParamPDE_85478439125433_kernel<<<grid, block, 0, stream>>>(
        state, bc, a_org, b_org, k_org, out);
}

// Round 3
// 242.739 us; speedup vs baseline: 1.0029x; 1.0029x over previous
//
#include <hip/hip_runtime.h>

#define NXD 4096
#define NYD 4096

typedef float f32x4 __attribute__((ext_vector_type(4)));

// R3: full-row blocks (1024 thr x 4 cols = 4096 cols = one row-pair per block).
//  - Kills ALL per-lane global edge loads (they were 32 tiny VMEM reqs/block,
//    ~half the CU's outstanding-request slots for 0.4% of bytes). Horizontal
//    neighbors now come from an LDS column exchange (stride-1, conflict-free)
//    or from bc at the true domain boundary.
//  - 1024-thread blocks dodge the ~5-workgroups/CU cap seen at 64% occupancy:
//    2 blocks/CU x 16 waves = 32 waves/CU (full).
// 8 fat float4 loads per thread stay issued back-to-back up front (R1 winner).
__global__ __launch_bounds__(1024) void DiffReactParamPDE_85478439125433_kernel(
    const float* __restrict__ state,
    const float* __restrict__ bc,
    const float* __restrict__ a_org,
    const float* __restrict__ b_org,
    const float* __restrict__ k_org,
    float* __restrict__ out)
{
    const float inv_dx2 = 100.0f;

    const int tid = threadIdx.x;          // 0..1023
    const int j0  = tid * 4;              // 4 cols per thread, full row per block
    const int i0  = blockIdx.x * 2;       // row pair

    const float* __restrict__ U = state;
    const float* __restrict__ V = state + (size_t)NXD * NYD;
    float* __restrict__ dU = out;
    float* __restrict__ dV = out + (size_t)NXD * NYD;

    // Clamp halo rows so all 8 loads issue unconditionally; bc-patch later.
    const int rT = (i0 == 0) ? 0 : i0 - 1;
    const int rB = (i0 + 2 >= NXD) ? NXD - 1 : i0 + 2;

#define LD4(P, ROW) (*(const float4*)((P) + (size_t)(ROW) * NYD + j0))
    // ---- 8 fat loads, issued back-to-back ----
    float4 um = LD4(U, rT);
    float4 u0 = LD4(U, i0);
    float4 u1 = LD4(U, i0 + 1);
    float4 up = LD4(U, rB);
    float4 vm = LD4(V, rT);
    float4 v0 = LD4(V, i0);
    float4 v1 = LD4(V, i0 + 1);
    float4 vp = LD4(V, rB);
#undef LD4

    // bc (1,2,4): [U: L,R,T,B | V: L,R,T,B] -- uniform -> scalar loads
    const float uL = bc[0], uR = bc[1], uT = bc[2], uB = bc[3];
    const float vL = bc[4], vR = bc[5], vT = bc[6], vB = bc[7];

    // scalar params overlap with the vector loads
    const float a = 0.01f / (1.0f + expf(-a_org[0]));
    const float b = 0.01f / (1.0f + expf(-b_org[0]));
    const float k = 0.01f / (1.0f + expf(-k_org[0]));

    // ---- LDS column exchange: first (.x) and last (.w) element of each
    // thread's 4-col chunk, for both compute rows of both fields. ----
    __shared__ float sx[8][1024];  // [u0x,u0w,u1x,u1w,v0x,v0w,v1x,v1w]
    sx[0][tid] = u0.x;  sx[1][tid] = u0.w;
    sx[2][tid] = u1.x;  sx[3][tid] = u1.w;
    sx[4][tid] = v0.x;  sx[5][tid] = v0.w;
    sx[6][tid] = v1.x;  sx[7][tid] = v1.w;
    __syncthreads();

    // horizontal neighbors: interior from LDS, domain edge from bc
    const int tm = (tid == 0)    ? 0    : tid - 1;
    const int tp = (tid == 1023) ? 1023 : tid + 1;
    float ulft0 = (tid == 0)    ? uL : sx[1][tm];
    float urgt0 = (tid == 1023) ? uR : sx[0][tp];
    float ulft1 = (tid == 0)    ? uL : sx[3][tm];
    float urgt1 = (tid == 1023) ? uR : sx[2][tp];
    float vlft0 = (tid == 0)    ? vL : sx[5][tm];
    float vrgt0 = (tid == 1023) ? vR : sx[4][tp];
    float vlft1 = (tid == 0)    ? vL : sx[7][tm];
    float vrgt1 = (tid == 1023) ? vR : sx[6][tp];

    // ---- patch vertical halo rows with bc (block-uniform branches) ----
    if (i0 == 0) {
        um = make_float4(uT, uT, uT, uT);
        vm = make_float4(vT, vT, vT, vT);
    }
    if (i0 + 2 >= NXD) {
        up = make_float4(uB, uB, uB, uB);
        vp = make_float4(vB, vB, vB, vB);
    }

    // =================== row 0 (i0): neighbors um / u1 ===================
    {
        const float lu0 = (um.x + u1.x + ulft0 + u0.y - 4.0f * u0.x) * inv_dx2;
        const float lu1 = (um.y + u1.y + u0.x  + u0.z - 4.0f * u0.y) * inv_dx2;
        const float lu2 = (um.z + u1.z + u0.y  + u0.w - 4.0f * u0.z) * inv_dx2;
        const float lu3 = (um.w + u1.w + u0.z  + urgt0 - 4.0f * u0.w) * inv_dx2;

        const float lv0 = (vm.x + v1.x + vlft0 + v0.y - 4.0f * v0.x) * inv_dx2;
        const float lv1 = (vm.y + v1.y + v0.x  + v0.z - 4.0f * v0.y) * inv_dx2;
        const float lv2 = (vm.z + v1.z + v0.y  + v0.w - 4.0f * v0.z) * inv_dx2;
        const float lv3 = (vm.w + v1.w + v0.z  + vrgt0 - 4.0f * v0.w) * inv_dx2;

        f32x4 duo, dvo;
        duo.x = a * lu0 + u0.x - u0.x * u0.x * u0.x - v0.x - k;
        duo.y = a * lu1 + u0.y - u0.y * u0.y * u0.y - v0.y - k;
        duo.z = a * lu2 + u0.z - u0.z * u0.z * u0.z - v0.z - k;
        duo.w = a * lu3 + u0.w - u0.w * u0.w * u0.w - v0.w - k;

        dvo.x = b * lv0 + u0.x - v0.x;
        dvo.y = b * lv1 + u0.y - v0.y;
        dvo.z = b * lv2 + u0.z - v0.z;
        dvo.w = b * lv3 + u0.w - v0.w;

        const size_t bo = (size_t)i0 * NYD + j0;
        __builtin_nontemporal_store(duo, (f32x4*)(dU + bo));
        __builtin_nontemporal_store(dvo, (f32x4*)(dV + bo));
    }

    // =================== row 1 (i0+1): neighbors u0 / up ===================
    {
        const float lu0 = (u0.x + up.x + ulft1 + u1.y - 4.0f * u1.x) * inv_dx2;
        const float lu1 = (u0.y + up.y + u1.x  + u1.z - 4.0f * u1.y) * inv_dx2;
        const float lu2 = (u0.z + up.z + u1.y  + u1.w - 4.0f * u1.z) * inv_dx2;
        const float lu3 = (u0.w + up.w + u1.z  + urgt1 - 4.0f * u1.w) * inv_dx2;

        const float lv0 = (v0.x + vp.x + vlft1 + v1.y - 4.0f * v1.x) * inv_dx2;
        const float lv1 = (v0.y + vp.y + v1.x  + v1.z - 4.0f * v1.y) * inv_dx2;
        const float lv2 = (v0.z + vp.z + v1.y  + v1.w - 4.0f * v1.z) * inv_dx2;
        const float lv3 = (v0.w + vp.w + v1.z  + vrgt1 - 4.0f * v1.w) * inv_dx2;

        f32x4 duo, dvo;
        duo.x = a * lu0 + u1.x - u1.x * u1.x * u1.x - v1.x - k;
        duo.y = a * lu1 + u1.y - u1.y * u1.y * u1.y - v1.y - k;
        duo.z = a * lu2 + u1.z - u1.z * u1.z * u1.z - v1.z - k;
        duo.w = a * lu3 + u1.w - u1.w * u1.w * u1.w - v1.w - k;

        dvo.x = b * lv0 + u1.x - v1.x;
        dvo.y = b * lv1 + u1.y - v1.y;
        dvo.z = b * lv2 + u1.z - v1.z;
        dvo.w = b * lv3 + u1.w - v1.w;

        const size_t bo = (size_t)(i0 + 1) * NYD + j0;
        __builtin_nontemporal_store(duo, (f32x4*)(dU + bo));
        __builtin_nontemporal_store(dvo, (f32x4*)(dV + bo));
    }
}

extern "C" void kernel_launch(void* const* d_in, const int* in_sizes, int n_in,
                              void* d_out, int out_size, void* d_ws, size_t ws_size,
                              hipStream_t stream) {
    const float* state = (const float*)d_in[0];
    const float* bc    = (const float*)d_in[1];
    const float* a_org = (const float*)d_in[2];
    const float* b_org = (const float*)d_in[3];
    const float* k_org = (const float*)d_in[4];
    float* out = (float*)d_out;

    // one block per row-pair: 2048 blocks x 1024 threads
    dim3 block(1024, 1, 1);
    dim3 grid(NXD / 2, 1, 1);
    DiffReactParamPDE_85478439125433_kernel<<<grid, block, 0, stream>>>(
        state, bc, a_org, b_org, k_org, out);
}

// Round 4
// 235.049 us; speedup vs baseline: 1.0358x; 1.0327x over previous
//
#include <hip/hip_runtime.h>

#define NXD 4096
#define NYD 4096
#define ROWS 8

typedef float f32x4 __attribute__((ext_vector_type(4)));

// R4 = R0 structure (ROWS=8 rolling window, 1.25x halo amplification)
//    + R1 lesson (deep load pipeline: queue-depth-2 prefetch, 4 fat loads
//      in flight per wave instead of R0's 2).
// Theory: R1-R3's ~80us plateau is LLC/fabric-side volume (2x halo ampl at
// ROWS=2 -> 399 MB L1-level demand at the measured ~5 TB/s request ceiling).
// Keeping ROWS=8 cuts L1-level demand back to 298 MB; the prefetch queue
// keeps the request stream at R1's throughput -> ~55-65us predicted.
__global__ __launch_bounds__(256) void DiffReactParamPDE_85478439125433_kernel(
    const float* __restrict__ state,
    const float* __restrict__ bc,
    const float* __restrict__ a_org,
    const float* __restrict__ b_org,
    const float* __restrict__ k_org,
    float* __restrict__ out)
{
    const float inv_dx2 = 100.0f;

    const int lane = threadIdx.x & 63;
    const int j0 = (blockIdx.x * 256 + threadIdx.x) * 4;  // 4 cols per thread
    const int i0 = blockIdx.y * ROWS;                     // first output row

    const float* __restrict__ U = state;
    const float* __restrict__ V = state + (size_t)NXD * NYD;
    float* __restrict__ dU = out;
    float* __restrict__ dV = out + (size_t)NXD * NYD;

    const int rT = (i0 == 0) ? 0 : i0 - 1;

#define LD4(P, ROW) (*(const float4*)((P) + (size_t)(ROW) * NYD + j0))
    // ---- prologue: 8 fat loads back-to-back (rows i0-1 .. i0+2) ----
    // i0 <= 4088 so i0+2 <= 4090: no clamp needed here.
    float4 um = LD4(U, rT);
    float4 uc = LD4(U, i0);
    float4 up = LD4(U, i0 + 1);
    float4 uq = LD4(U, i0 + 2);   // queue: row i0+2
    float4 vm = LD4(V, rT);
    float4 vc = LD4(V, i0);
    float4 vp = LD4(V, i0 + 1);
    float4 vq = LD4(V, i0 + 2);

    // bc (1,2,4): [U: L,R,T,B | V: L,R,T,B] -- uniform -> scalar loads
    const float uL = bc[0], uR = bc[1], uT = bc[2], uB = bc[3];
    const float vL = bc[4], vR = bc[5], vT = bc[6], vB = bc[7];

    const float4 fuT = make_float4(uT, uT, uT, uT), fuB = make_float4(uB, uB, uB, uB);
    const float4 fvT = make_float4(vT, vT, vT, vT), fvB = make_float4(vB, vB, vB, vB);

    // edge scalars for the first compute row (lanes 0/63 only)
    float eLu = uL, eRu = uR, eLv = vL, eRv = vR;
    if (lane == 0 && j0 > 0) {
        eLu = U[(size_t)i0 * NYD + j0 - 1];
        eLv = V[(size_t)i0 * NYD + j0 - 1];
    }
    if (lane == 63 && j0 + 4 < NYD) {
        eRu = U[(size_t)i0 * NYD + j0 + 4];
        eRv = V[(size_t)i0 * NYD + j0 + 4];
    }

    // scalar params (uniform) overlap with the loads above
    const float a = 0.01f / (1.0f + expf(-a_org[0]));
    const float b = 0.01f / (1.0f + expf(-b_org[0]));
    const float k = 0.01f / (1.0f + expf(-k_org[0]));

    // top boundary patch (block-uniform)
    if (i0 == 0) { um = fuT; vm = fvT; }

#pragma unroll
    for (int r = 0; r < ROWS; ++r) {
        const int row = i0 + r;

        // ---- prefetch row+3 into the queue tail (compile-time guard) ----
        float4 unew = uq, vnew = vq;
        if (r < ROWS - 2) {
            int rq = row + 3;
            if (rq >= NXD) rq = NXD - 1;   // last block only; patched at use
            unew = LD4(U, rq);
            vnew = LD4(V, rq);
        }

        // ---- prefetch next row's edge scalars ----
        float eLu_n = uL, eRu_n = uR, eLv_n = vL, eRv_n = vR;
        if (r < ROWS - 1) {
            if (lane == 0 && j0 > 0) {
                eLu_n = U[(size_t)(row + 1) * NYD + j0 - 1];
                eLv_n = V[(size_t)(row + 1) * NYD + j0 - 1];
            }
            if (lane == 63 && j0 + 4 < NYD) {
                eRu_n = U[(size_t)(row + 1) * NYD + j0 + 4];
                eRv_n = V[(size_t)(row + 1) * NYD + j0 + 4];
            }
        }

        // bottom boundary patch (true only for last block, r == ROWS-1)
        if (row + 1 == NXD) { up = fuB; vp = fvB; }

        // ---- horizontal neighbors via cross-lane shuffle ----
        float ulft = __shfl_up(uc.w, 1);   if (lane == 0)  ulft = eLu;
        float urgt = __shfl_down(uc.x, 1); if (lane == 63) urgt = eRu;
        float vlft = __shfl_up(vc.w, 1);   if (lane == 0)  vlft = eLv;
        float vrgt = __shfl_down(vc.x, 1); if (lane == 63) vrgt = eRv;

        // ---- Laplacians ----
        const float lu0 = (um.x + up.x + ulft + uc.y - 4.0f * uc.x) * inv_dx2;
        const float lu1 = (um.y + up.y + uc.x + uc.z - 4.0f * uc.y) * inv_dx2;
        const float lu2 = (um.z + up.z + uc.y + uc.w - 4.0f * uc.z) * inv_dx2;
        const float lu3 = (um.w + up.w + uc.z + urgt - 4.0f * uc.w) * inv_dx2;

        const float lv0 = (vm.x + vp.x + vlft + vc.y - 4.0f * vc.x) * inv_dx2;
        const float lv1 = (vm.y + vp.y + vc.x + vc.z - 4.0f * vc.y) * inv_dx2;
        const float lv2 = (vm.z + vp.z + vc.y + vc.w - 4.0f * vc.z) * inv_dx2;
        const float lv3 = (vm.w + vp.w + vc.z + vrgt - 4.0f * vc.w) * inv_dx2;

        f32x4 duo, dvo;
        duo.x = a * lu0 + uc.x - uc.x * uc.x * uc.x - vc.x - k;
        duo.y = a * lu1 + uc.y - uc.y * uc.y * uc.y - vc.y - k;
        duo.z = a * lu2 + uc.z - uc.z * uc.z * uc.z - vc.z - k;
        duo.w = a * lu3 + uc.w - uc.w * uc.w * uc.w - vc.w - k;

        dvo.x = b * lv0 + uc.x - vc.x;
        dvo.y = b * lv1 + uc.y - vc.y;
        dvo.z = b * lv2 + uc.z - vc.z;
        dvo.w = b * lv3 + uc.w - vc.w;

        const size_t bo = (size_t)row * NYD + j0;
        __builtin_nontemporal_store(duo, (f32x4*)(dU + bo));
        __builtin_nontemporal_store(dvo, (f32x4*)(dV + bo));

        // ---- shift window + queue ----
        um = uc; uc = up; up = uq; uq = unew;
        vm = vc; vc = vp; vp = vq; vq = vnew;
        eLu = eLu_n; eRu = eRu_n; eLv = eLv_n; eRv = eRv_n;
    }
#undef LD4
}

extern "C" void kernel_launch(void* const* d_in, const int* in_sizes, int n_in,
                              void* d_out, int out_size, void* d_ws, size_t ws_size,
                              hipStream_t stream) {
    const float* state = (const float*)d_in[0];
    const float* bc    = (const float*)d_in[1];
    const float* a_org = (const float*)d_in[2];
    const float* b_org = (const float*)d_in[3];
    const float* k_org = (const float*)d_in[4];
    float* out = (float*)d_out;

    // 256 threads x 4 cols = 1024 cols/block -> 4 x-blocks; 4096/ROWS y-blocks
    dim3 block(256, 1, 1);
    dim3 grid(NYD / (4 * 256), NXD / ROWS, 1);
    DiffReactParamPDE_85478439125433_kernel<<<grid, block, 0, stream>>>(
        state, bc, a_org, b_org, k_org, out);
}